// Round 5
// baseline (54.352 us; speedup 1.0000x reference)
//
#include <hip/hip_runtime.h>

#define T_CNT   128
#define IOU_TH  0.4f
#define K_CONST 2.5f
#define NB_A    512    // role-A blocks: per-prior max + baseline sums
#define NB_B    1024   // role-B blocks: per-truth argmax
#define PPT     2      // priors per thread, role A
#define CB      256    // priors per block, role B

// ws layout:
//   [0,32)        double accum[3]: S1=sum(sig), S2=sum(xf), S3=sum(sig*xf*log(bto))
//   [64,1088)     unsigned long long packed[128]: (iou_bits<<32) | ~prior_idx
//   [4096, +P*4)  float bto[P]
static const size_t WS_ACC_OFF    = 0;
static const size_t WS_PACKED_OFF = 64;
static const size_t WS_BTO_OFF    = 4096;

// One dispatch, two block roles. Each role uses the layout in which its
// reduction axis needs no cross-lane work in the hot loop.
__global__ __launch_bounds__(256) void apb_work(
    const float* __restrict__ locs, const float* __restrict__ params,
    const float* __restrict__ truths, float* __restrict__ bto,
    unsigned long long* __restrict__ packed, double* __restrict__ accum)
{
    const int tid = threadIdx.x;

    if (blockIdx.x < NB_A) {
        // ---- role A: lane = prior, broadcast truths; per-prior running max.
        __shared__ float4 s_tb[T_CNT];
        __shared__ float  s_red[3][4];

        if (tid < T_CNT) s_tb[tid] = ((const float4*)truths)[tid];
        __syncthreads();

        const int base = blockIdx.x * (256 * PPT);

        float px1[PPT], py1[PPT], px2[PPT], py2[PPT], parea[PPT];
#pragma unroll
        for (int k = 0; k < PPT; ++k) {
            int p = base + k * 256 + tid;
            float2 c = ((const float2*)locs)[p];
            float w = params[3 * p];
            float h = params[3 * p + 1];
            px1[k] = c.x - 0.5f * w; py1[k] = c.y - 0.5f * h;
            px2[k] = c.x + 0.5f * w; py2[k] = c.y + 0.5f * h;
            parea[k] = (px2[k] - px1[k]) * (py2[k] - py1[k]);  // corner-form, exact ref match
        }

        float btmax[PPT];
#pragma unroll
        for (int k = 0; k < PPT; ++k) btmax[k] = 0.f;

#pragma unroll 2
        for (int t = 0; t < T_CNT; ++t) {
            float4 tb = s_tb[t];                       // broadcast: conflict-free
            float ta = (tb.z - tb.x) * (tb.w - tb.y);
#pragma unroll
            for (int k = 0; k < PPT; ++k) {
                float lx = fmaxf(tb.x, px1[k]);
                float ly = fmaxf(tb.y, py1[k]);
                float rx = fminf(tb.z, px2[k]);
                float ry = fminf(tb.w, py2[k]);
                float w = fmaxf(rx - lx, 0.f);
                float h = fmaxf(ry - ly, 0.f);
                float inter = w * h;
                float iou = inter * __builtin_amdgcn_rcpf((ta + parea[k]) - inter);
                btmax[k] = fmaxf(btmax[k], iou);
            }
        }

        // epilogue: baseline sums + bto write
        float s1 = 0.f, s2 = 0.f, s3 = 0.f;
#pragma unroll
        for (int k = 0; k < PPT; ++k) {
            int p = base + k * 256 + tid;
            float a = params[3 * p + 2];
            float sig = 1.f / (1.f + expf(-a));
            float bt = btmax[k];
            float xf = (bt > IOU_TH) ? 1.f : 0.f;
            s1 += sig;
            s2 += xf;
            s3 += (xf > 0.f) ? sig * logf(bt) : 0.f;
            bto[p] = bt;
        }
#pragma unroll
        for (int off = 32; off; off >>= 1) {
            s1 += __shfl_xor(s1, off, 64);
            s2 += __shfl_xor(s2, off, 64);
            s3 += __shfl_xor(s3, off, 64);
        }
        const int wv = tid >> 6;
        if ((tid & 63) == 0) { s_red[0][wv] = s1; s_red[1][wv] = s2; s_red[2][wv] = s3; }
        __syncthreads();
        if (tid == 0) {
            atomicAdd(&accum[0], (double)(s_red[0][0] + s_red[0][1] + s_red[0][2] + s_red[0][3]));
            atomicAdd(&accum[1], (double)(s_red[1][0] + s_red[1][1] + s_red[1][2] + s_red[1][3]));
            atomicAdd(&accum[2], (double)(s_red[2][0] + s_red[2][1] + s_red[2][2] + s_red[2][3]));
        }
    } else {
        // ---- role B: lane = truth (2/lane), broadcast one prior per iter.
        // Priors partitioned across waves: zero cross-lane work in the loop.
        __shared__ float4 s_p[CB];
        __shared__ unsigned long long s_part[4][T_CNT];

        const int base = (blockIdx.x - NB_A) * CB;
        {
            int p = base + tid;
            float2 c = ((const float2*)locs)[p];
            float w = params[3 * p];
            float h = params[3 * p + 1];
            s_p[tid] = make_float4(c.x - 0.5f * w, c.y - 0.5f * h,
                                   c.x + 0.5f * w, c.y + 0.5f * h);
        }
        const int lane = tid & 63;
        float4 t0 = ((const float4*)truths)[lane];
        float4 t1 = ((const float4*)truths)[64 + lane];
        float ta0 = (t0.z - t0.x) * (t0.w - t0.y);
        float ta1 = (t1.z - t1.x) * (t1.w - t1.y);
        __syncthreads();

        const int wv = tid >> 6;
        const int wbase = wv * (CB / 4);
        float maxv0 = -1.f, maxv1 = -1.f;
        unsigned int maxi0 = 0u, maxi1 = 0u;

#pragma unroll 4
        for (int j = 0; j < CB / 4; ++j) {
            float4 pb = s_p[wbase + j];                 // wave-uniform broadcast
            float parea = (pb.z - pb.x) * (pb.w - pb.y);
            unsigned int pg = (unsigned int)(base + wbase + j);  // wave-uniform -> SGPR
            {
                float lx = fmaxf(t0.x, pb.x);
                float ly = fmaxf(t0.y, pb.y);
                float rx = fminf(t0.z, pb.z);
                float ry = fminf(t0.w, pb.w);
                float w = fmaxf(rx - lx, 0.f);
                float h = fmaxf(ry - ly, 0.f);
                float inter = w * h;
                float iou = inter * __builtin_amdgcn_rcpf((ta0 + parea) - inter);
                if (iou > maxv0) { maxv0 = iou; maxi0 = pg; }  // strict >: first occurrence
            }
            {
                float lx = fmaxf(t1.x, pb.x);
                float ly = fmaxf(t1.y, pb.y);
                float rx = fminf(t1.z, pb.z);
                float ry = fminf(t1.w, pb.w);
                float w = fmaxf(rx - lx, 0.f);
                float h = fmaxf(ry - ly, 0.f);
                float inter = w * h;
                float iou = inter * __builtin_amdgcn_rcpf((ta1 + parea) - inter);
                if (iou > maxv1) { maxv1 = iou; maxi1 = pg; }
            }
        }

        s_part[wv][lane] =
            ((unsigned long long)__float_as_uint(maxv0) << 32) |
            (unsigned long long)(~maxi0);
        s_part[wv][64 + lane] =
            ((unsigned long long)__float_as_uint(maxv1) << 32) |
            (unsigned long long)(~maxi1);
        __syncthreads();

        if (tid < T_CNT) {
            unsigned long long m = s_part[0][tid];
            unsigned long long a = s_part[1][tid];
            unsigned long long b = s_part[2][tid];
            unsigned long long c = s_part[3][tid];
            m = (a > m) ? a : m;
            m = (b > m) ? b : m;
            m = (c > m) ? c : m;
            atomicMax(&packed[tid], m);
        }
    }
}

// ---------------- Finalize: scatter corrections + scalar loss --------------
__global__ __launch_bounds__(128) void apb_final(
    const float* __restrict__ params, const float* __restrict__ bto,
    const unsigned long long* __restrict__ packed,
    const double* __restrict__ accum, float* __restrict__ out)
{
    const int t = threadIdx.x;
    __shared__ unsigned int s_idx[T_CNT];

    unsigned long long v = packed[t];
    float ov = __uint_as_float((unsigned int)(v >> 32));     // best_prior_overlap[t]
    unsigned int p = ~(unsigned int)(v & 0xFFFFFFFFull);     // best_prior_idx[t]
    s_idx[t] = p;
    __syncthreads();

    // numpy fancy-assignment semantics: duplicate indices -> last t wins
    bool is_last = true;
    for (int u = t + 1; u < T_CNT; ++u)
        if (s_idx[u] == p) is_last = false;

    float c2 = 0.f, c3 = 0.f;
    if (is_last && v != 0ull) {
        float old = bto[p];
        float oxf = (old > IOU_TH) ? 1.f : 0.f;
        float a = params[3 * p + 2];
        float sig = 1.f / (1.f + expf(-a));
        float oldterm = (oxf > 0.f) ? sig * logf(old) : 0.f;
        float newterm = K_CONST * sig * logf(ov);
        c3 = newterm - oldterm;
        c2 = K_CONST - oxf;
    }

#pragma unroll
    for (int off = 32; off; off >>= 1) {
        c2 += __shfl_xor(c2, off, 64);
        c3 += __shfl_xor(c3, off, 64);
    }
    __shared__ float sw[4];
    if ((t & 63) == 0) { sw[(t >> 6) * 2] = c2; sw[(t >> 6) * 2 + 1] = c3; }
    __syncthreads();

    if (t == 0) {
        double S1 = accum[0];
        double S2 = accum[1] + (double)(sw[0] + sw[2]);
        double S3 = accum[2] + (double)(sw[1] + sw[3]);
        out[0] = (float)((S1 - S3) / S2);  // BETA = 1.0
    }
}

extern "C" void kernel_launch(void* const* d_in, const int* in_sizes, int n_in,
                              void* d_out, int out_size, void* d_ws, size_t ws_size,
                              hipStream_t stream) {
    const float* locs   = (const float*)d_in[0];
    const float* params = (const float*)d_in[1];
    const float* truths = (const float*)d_in[2];

    double* accum = (double*)((char*)d_ws + WS_ACC_OFF);
    unsigned long long* packed = (unsigned long long*)((char*)d_ws + WS_PACKED_OFF);
    float* bto = (float*)((char*)d_ws + WS_BTO_OFF);

    // ws is poisoned 0xAA and never re-poisoned: zero accum + packed each call
    hipMemsetAsync(d_ws, 0, 1088, stream);

    apb_work<<<NB_A + NB_B, 256, 0, stream>>>(locs, params, truths, bto, packed, accum);
    apb_final<<<1, 128, 0, stream>>>(params, bto, packed, accum, (float*)d_out);
}